// Round 12
// baseline (90.662 us; speedup 1.0000x reference)
//
#include <hip/hip_runtime.h>
#include <math.h>

#define NNODE 512
#define NBATCH 4
#define NFEAT 12
#define QKD 128
#define NVD 128
#define EVD 32
#define CATD 160          // NVD + EVD
#define CATB 168          // catb LDS stride (bf16)
#define TRD 256
#define NCLS 5
#define NROWS 2048        // NBATCH * NNODE
#define EPSV 1e-5f
#define NSTATBUF 8        // split BN-stat atomic contention 8 ways
#define NCHUNK 4          // j-chunks (online-softmax loop)
#define JC 128            // j-chunk width
#define RPB 8             // query rows per attnTrans block
#define SSW 132           // sS row stride (f32)
#define KBW 136           // K/NV LDS row stride (ushort)

typedef float floatx4 __attribute__((ext_vector_type(4)));
typedef __bf16 bf16x8 __attribute__((ext_vector_type(8)));
typedef unsigned short ushort_t;
typedef ushort_t ushort8 __attribute__((ext_vector_type(8)));
typedef ushort_t ushort4v __attribute__((ext_vector_type(4)));

// f32 -> bf16 bits, round-to-nearest-even
static __device__ __forceinline__ ushort_t f2bf(float x) {
  unsigned int u = __float_as_uint(x);
  return (ushort_t)((u + 0x7fffu + ((u >> 16) & 1u)) >> 16);
}
static __device__ __forceinline__ bf16x8 pack8(ushort4v lo, ushort4v hi) {
  ushort8 u;
  u[0] = lo.x; u[1] = lo.y; u[2] = lo.z; u[3] = lo.w;
  u[4] = hi.x; u[5] = hi.y; u[6] = hi.z; u[7] = hi.w;
  return __builtin_bit_cast(bf16x8, u);
}

// ---------------------------------------------------------------------------
// Kernel 1: projections -> bf16 Qb[row][d], Kb[row][d], NVT[b][d][j],
// Wtb (bf16 Wt). 256 blocks x 256 thr, 8 rows/block. Blocks 0..15 zero stats.
// ---------------------------------------------------------------------------
__global__ __launch_bounds__(256) void qkv_kernel(
    const float* __restrict__ nodes,
    const float* __restrict__ Wq, const float* __restrict__ bq,
    const float* __restrict__ Wk, const float* __restrict__ bk,
    const float* __restrict__ Wnv, const float* __restrict__ bnv,
    const float* __restrict__ Wt,
    ushort_t* __restrict__ Qb, ushort_t* __restrict__ Kb,
    ushort_t* __restrict__ NVT, ushort_t* __restrict__ Wtb,
    float* __restrict__ stats) {
  const int tid = threadIdx.x;
  const int blk = blockIdx.x;           // 0..255
  const int rowbase = blk * 8;
  const int b = rowbase >> 9;
  const int jloc = rowbase & (NNODE - 1);
  if (blk < 2 * NSTATBUF) stats[blk * 256 + tid] = 0.f;   // 16x256 = 4096
  {  // Wt -> bf16: 40960 elems, 160 per block
    const int base = blk * 160;
    if (tid < 160) Wtb[base + tid] = f2bf(Wt[base + tid]);
  }
  __shared__ float sn[RPB][NFEAT];
  if (tid < RPB * NFEAT) ((float*)sn)[tid] = nodes[(size_t)rowbase * NFEAT + tid];
  __syncthreads();

  // ---- Q/K: thread owns d = tid&127; rows (tid>>7)*4 .. +3 --------------
  {
    const int d  = tid & 127;
    const int rg = tid >> 7;
    float wq[NFEAT], wk[NFEAT];
#pragma unroll
    for (int k = 0; k < NFEAT; ++k) {
      wq[k] = Wq[d * NFEAT + k];
      wk[k] = Wk[d * NFEAT + k];
    }
    const float bqv = bq[d], bkv = bk[d];
#pragma unroll
    for (int rr = 0; rr < 4; ++rr) {
      const int rl = rg * 4 + rr;
      float aq = bqv, ak = bkv;
#pragma unroll
      for (int k = 0; k < NFEAT; ++k) {
        const float n = sn[rl][k];
        aq = fmaf(n, wq[k], aq);
        ak = fmaf(n, wk[k], ak);
      }
      Qb[(size_t)(rowbase + rl) * QKD + d] = f2bf(aq);
      Kb[(size_t)(rowbase + rl) * QKD + d] = f2bf(ak);
    }
  }
  // ---- NV^T: thread owns d = tid>>1, half = tid&1 (4 j each) ------------
  {
    const int d    = tid >> 1;
    const int half = tid & 1;
    float wnv[NFEAT];
#pragma unroll
    for (int k = 0; k < NFEAT; ++k) wnv[k] = Wnv[d * NFEAT + k];
    const float bnvv = bnv[d];
    ushort4v v;
#pragma unroll
    for (int e = 0; e < 4; ++e) {
      const int rl = half * 4 + e;
      float av = bnvv;
#pragma unroll
      for (int k = 0; k < NFEAT; ++k) av = fmaf(sn[rl][k], wnv[k], av);
      v[e] = f2bf(av);
    }
    *(ushort4v*)(NVT + (size_t)b * QKD * NNODE + (size_t)d * NNODE +
                 jloc + half * 4) = v;
  }
}

// ---------------------------------------------------------------------------
// Kernel 2: attnTrans — flash attention (online softmax over 4 chunks) fused
// with the tanh+transform MFMA and BN-stat atomics. (R9 body, verbatim.)
// 256 blocks (1/CU) x 512 thr (8 waves); block = 8 query rows x all 512 j.
// ---------------------------------------------------------------------------
__global__ __launch_bounds__(512) void attnTrans_kernel(
    const ushort_t* __restrict__ Qb, const ushort_t* __restrict__ Kb,
    const ushort_t* __restrict__ NVT,
    const float* __restrict__ edges, const float* __restrict__ dist,
    const int* __restrict__ mask,
    const float* __restrict__ Wev, const float* __restrict__ bev,
    const ushort_t* __restrict__ Wtb, const float* __restrict__ bt,
    float* __restrict__ vals, float* __restrict__ stats) {
  __shared__ ushort_t sKB[JC * KBW];          // 34.8 KB
  __shared__ ushort_t sNV[2][QKD * KBW];      // 69.6 KB (double-buffered)
  __shared__ __align__(16) float sS[16][SSW]; // 8.4 KB (scores -> w)
  __shared__ ushort_t catb[RPB * CATB];       // 2.7 KB
  __shared__ float sF[16], sF2[RPB], sSe[RPB], sSw[RPB];

  const int tid = threadIdx.x;
  const int bid = blockIdx.x;            // 0..255
  const int b   = bid >> 6;              // batch
  const int rg  = bid & 63;              // row group
  const int rowbase = b * NNODE + rg * RPB;

  const int lane = tid & 63;
  const int wv   = tid >> 6;             // wave 0..7
  const int col  = lane & 15;
  const int kg   = lane >> 4;

  if (tid < 16) sF[tid] = 0.f;           // rows 8..15 stay 0 forever

  // ---- Q A-fragments (rows constant across chunks) ----------------------
  bf16x8 aq[4];
  {
    const ushort_t* Qr = Qb + (size_t)(rowbase + (col & 7)) * QKD;
#pragma unroll
    for (int ks = 0; ks < 4; ++ks)
      aq[ks] = pack8(*(const ushort4v*)(Qr + ks * 32 + kg * 4),
                     *(const ushort4v*)(Qr + ks * 32 + 16 + kg * 4));
  }

  const int sd   = tid >> 2;             // staging row 0..127
  const int sseg = (tid & 3) * 32;       // 32-ushort segment
  const int jl   = wv * 16 + col;        // this thread's chunk-local j (QK^T)
  const int dpv  = wv * 16 + col;        // this thread's d column (PV)

  float m_run = -__builtin_inff(), l_run = 0.f, se_run = 0.f;  // row = wv
  floatx4 acc = {0.f, 0.f, 0.f, 0.f};    // PV accumulator (rows kg*4+r, col dpv)
  const float coeff = 0.0883883476483184f;  // 1/sqrt(128)

  for (int c = 0; c < NCHUNK; ++c) {
    const int jbase = c * JC;
    // ---- prefetch dist/mask (score positions) + edges (softmax row wv) --
    float dd[4]; int mm[4];
#pragma unroll
    for (int r = 0; r < 4; ++r) {
      const size_t off =
          (size_t)(rowbase + ((kg * 4 + r) & 7)) * NNODE + jbase + jl;
      dd[r] = dist[off];
      mm[r] = mask[off];
    }
    const float e0 = edges[(size_t)(rowbase + wv) * NNODE + jbase + lane];
    const float e1 = edges[(size_t)(rowbase + wv) * NNODE + jbase + 64 + lane];

    // ---- stage K chunk -> sKB, NV chunk -> sNV[c&1] ---------------------
    {
      const ushort8* ksrc =
          (const ushort8*)(Kb + (size_t)(b * NNODE + jbase + sd) * QKD + sseg);
      ushort8* kdst = (ushort8*)(sKB + sd * KBW + sseg);
#pragma unroll
      for (int t = 0; t < 4; ++t) kdst[t] = ksrc[t];
      const ushort8* nsrc = (const ushort8*)(NVT + (size_t)b * QKD * NNODE +
                                             (size_t)sd * NNODE + jbase + sseg);
      ushort8* ndst = (ushort8*)(sNV[c & 1] + sd * KBW + sseg);
#pragma unroll
      for (int t = 0; t < 4; ++t) ndst[t] = nsrc[t];
    }
    __syncthreads();

    // ---- QK^T: wave owns j-tile wv; 4 MFMAs -----------------------------
    {
      floatx4 sc = {0.f, 0.f, 0.f, 0.f};
      const ushort_t* kb = sKB + (size_t)jl * KBW;
#pragma unroll
      for (int ks = 0; ks < 4; ++ks) {
        const bf16x8 bfk = pack8(*(const ushort4v*)(kb + ks * 32 + kg * 4),
                                 *(const ushort4v*)(kb + ks * 32 + 16 + kg * 4));
        sc = __builtin_amdgcn_mfma_f32_16x16x32_bf16(aq[ks], bfk, sc, 0, 0, 0);
      }
#pragma unroll
      for (int r = 0; r < 4; ++r) {
        float s = sc[r] * coeff / (dd[r] + 1.0f);
        if (mm[r]) s = -__builtin_inff();
        sS[kg * 4 + r][jl] = s;
      }
    }
    __syncthreads();

    // ---- online softmax: wave wv owns row wv ----------------------------
    {
      const float v0 = sS[wv][lane];
      const float v1 = sS[wv][lane + 64];
      float mc = fmaxf(v0, v1);
#pragma unroll
      for (int s = 1; s < 64; s <<= 1) mc = fmaxf(mc, __shfl_xor(mc, s, 64));
      const float mn = fmaxf(m_run, mc);
      const float f = (m_run > -__builtin_inff()) ? __expf(m_run - mn) : 0.f;
      float w0 = 0.f, w1 = 0.f;
      if (mn > -__builtin_inff()) {      // wave-uniform
        w0 = __expf(v0 - mn);
        w1 = __expf(v1 - mn);
      }
      sS[wv][lane]      = w0;
      sS[wv][lane + 64] = w1;
      float lc = w0 + w1;
      float sec = fmaf(w0, e0, w1 * e1);
#pragma unroll
      for (int s = 1; s < 64; s <<= 1) {
        lc  += __shfl_xor(lc, s, 64);
        sec += __shfl_xor(sec, s, 64);
      }
      l_run  = l_run * f + lc;
      se_run = se_run * f + sec;
      m_run  = mn;
      if (lane == 0) sF[wv] = f;
    }
    __syncthreads();

    // ---- PV: rescale acc, then acc += w(16x128) @ NV(128x d-tile) -------
    {
      acc[0] *= sF[kg * 4 + 0];
      acc[1] *= sF[kg * 4 + 1];
      acc[2] *= sF[kg * 4 + 2];
      acc[3] *= sF[kg * 4 + 3];
      const ushort_t* nv = sNV[c & 1] + (size_t)dpv * KBW;
#pragma unroll
      for (int ks = 0; ks < 4; ++ks) {
        const float4 lo = *(const float4*)&sS[col][ks * 32 + kg * 4];
        const float4 hi = *(const float4*)&sS[col][ks * 32 + 16 + kg * 4];
        ushort8 u;
        u[0] = f2bf(lo.x); u[1] = f2bf(lo.y); u[2] = f2bf(lo.z); u[3] = f2bf(lo.w);
        u[4] = f2bf(hi.x); u[5] = f2bf(hi.y); u[6] = f2bf(hi.z); u[7] = f2bf(hi.w);
        const bf16x8 aw = __builtin_bit_cast(bf16x8, u);
        const bf16x8 bnv = pack8(*(const ushort4v*)(nv + ks * 32 + kg * 4),
                                 *(const ushort4v*)(nv + ks * 32 + 16 + kg * 4));
        acc = __builtin_amdgcn_mfma_f32_16x16x32_bf16(aw, bnv, acc, 0, 0, 0);
      }
    }
  }

  // ---- epilogue: finalize row stats -------------------------------------
  {
    const float inv = (l_run > 0.f) ? 1.f / l_run : 0.f;
    if (lane == 0) {
      sF2[wv] = inv;
      sSe[wv] = se_run * inv;
      sSw[wv] = (l_run > 0.f) ? 1.f : 0.f;
    }
  }
  __syncthreads();

  // ---- normalize + tanh -> catb (bf16) ----------------------------------
  if (kg < 2) {
#pragma unroll
    for (int r = 0; r < 4; ++r) {
      const int row = kg * 4 + r;
      catb[row * CATB + dpv] = f2bf(tanhf(acc[r] * sF2[row]));
    }
  }
  if (tid < RPB * EVD) {                 // 256 edge elems
    const int r = tid >> 5, de = tid & 31;
    catb[r * CATB + NVD + de] =
        f2bf(tanhf(fmaf(Wev[de], sSe[r], bev[de] * sSw[r])));
  }
  __syncthreads();

  // ---- transform: vals = catb @ Wtb^T + bt; BN stat atomics --------------
  {
    bf16x8 af[5];
    const ushort_t* cr = catb + (size_t)(col & 7) * CATB;
#pragma unroll
    for (int ks = 0; ks < 5; ++ks)
      af[ks] = pack8(*(const ushort4v*)(cr + ks * 32 + kg * 4),
                     *(const ushort4v*)(cr + ks * 32 + 16 + kg * 4));
    float* sbuf = stats + (size_t)(bid & (NSTATBUF - 1)) * 2 * TRD;
#pragma unroll
    for (int t = 0; t < 2; ++t) {        // 16 col-tiles / 8 waves
      const int o = (wv * 2 + t) * 16 + col;
      const ushort_t* wr = Wtb + (size_t)o * CATD;
      floatx4 a2 = {0.f, 0.f, 0.f, 0.f};
#pragma unroll
      for (int ks = 0; ks < 5; ++ks) {
        const bf16x8 bf = pack8(*(const ushort4v*)(wr + ks * 32 + kg * 4),
                                *(const ushort4v*)(wr + ks * 32 + 16 + kg * 4));
        a2 = __builtin_amdgcn_mfma_f32_16x16x32_bf16(af[ks], bf, a2, 0, 0, 0);
      }
      const float bto = bt[o];
      float s1 = 0.f, s2 = 0.f;
#pragma unroll
      for (int r = 0; r < 4; ++r) {
        const float v2 = a2[r] + bto;
        if (kg < 2) {
          vals[(size_t)(rowbase + kg * 4 + r) * TRD + o] = v2;
          s1 += v2;
          s2 = fmaf(v2, v2, s2);
        }
      }
      s1 += __shfl_xor(s1, 16, 64); s2 += __shfl_xor(s2, 16, 64);
      s1 += __shfl_xor(s1, 32, 64); s2 += __shfl_xor(s2, 32, 64);
      if (kg == 0) {
        atomicAdd(&sbuf[o], s1);
        atomicAdd(&sbuf[TRD + o], s2);
      }
    }
  }
}

// ---------------------------------------------------------------------------
// Kernel 3: fused BN-fold + classifier. 512 blocks x 256 thr, 4 rows/block.
// ---------------------------------------------------------------------------
__global__ __launch_bounds__(256) void outbn_kernel(
    const float* __restrict__ vals, const float* __restrict__ stats,
    const float* __restrict__ gamma, const float* __restrict__ beta,
    const float* __restrict__ Wc, const float* __restrict__ bc,
    float* __restrict__ out) {
  __shared__ float sW[NCLS][TRD];
  __shared__ float sb[NCLS];
  __shared__ float red[4][NCLS];
  const int tid = threadIdx.x;
  const int o = tid;                   // 0..255
  float s1 = 0.f, s2 = 0.f;
#pragma unroll
  for (int k = 0; k < NSTATBUF; ++k) {
    s1 += stats[k * 2 * TRD + o];
    s2 += stats[k * 2 * TRD + TRD + o];
  }
  const float invN = 1.0f / (float)NROWS;
  const float mu  = s1 * invN;
  const float var = s2 * invN - mu * mu;
  const float inv = 1.0f / sqrtf(var + EPSV);
  const float g = gamma[o] * inv;
  const float bterm = beta[o] - mu * g;
  float v[NCLS];
#pragma unroll
  for (int c = 0; c < NCLS; ++c) {
    const float wc = Wc[c * TRD + o];
    sW[c][o] = wc * g;
    v[c] = wc * bterm;
  }
#pragma unroll
  for (int s = 1; s < 64; s <<= 1) {
#pragma unroll
    for (int c = 0; c < NCLS; ++c) v[c] += __shfl_xor(v[c], s, 64);
  }
  if ((tid & 63) == 0) {
#pragma unroll
    for (int c = 0; c < NCLS; ++c) red[tid >> 6][c] = v[c];
  }
  __syncthreads();
  if (tid < NCLS)
    sb[tid] = bc[tid] + red[0][tid] + red[1][tid] + red[2][tid] + red[3][tid];
  __syncthreads();

  const int lane = tid & 63;
  const int row = blockIdx.x * 4 + (tid >> 6);
  float vv[TRD / 64];
#pragma unroll
  for (int t = 0; t < TRD / 64; ++t)
    vv[t] = vals[(size_t)row * TRD + lane + 64 * t];
#pragma unroll
  for (int c = 0; c < NCLS; ++c) {
    float p = 0.f;
#pragma unroll
    for (int t = 0; t < TRD / 64; ++t)
      p = fmaf(vv[t], sW[c][lane + 64 * t], p);
#pragma unroll
    for (int s = 1; s < 64; s <<= 1) p += __shfl_xor(p, s, 64);
    if (lane == 0) out[(size_t)row * NCLS + c] = p + sb[c];
  }
}

// ---------------------------------------------------------------------------
// MEASUREMENT ROUND: attnTrans dispatched 4x (3 dummy-stats + 1 real) to read
// its per-dispatch time out of dur_us: T_attn = (dur - 34.2)/3.
// ---------------------------------------------------------------------------
extern "C" void kernel_launch(void* const* d_in, const int* in_sizes, int n_in,
                              void* d_out, int out_size, void* d_ws, size_t ws_size,
                              hipStream_t stream) {
  (void)in_sizes; (void)n_in; (void)out_size; (void)ws_size;
  const float* nodes = (const float*)d_in[0];
  const float* edges = (const float*)d_in[1];
  const float* dist  = (const float*)d_in[2];
  const int*   mask  = (const int*)d_in[3];
  const float* Wq  = (const float*)d_in[4];
  const float* bq  = (const float*)d_in[5];
  const float* Wk  = (const float*)d_in[6];
  const float* bk  = (const float*)d_in[7];
  const float* Wnv = (const float*)d_in[8];
  const float* bnv = (const float*)d_in[9];
  const float* Wev = (const float*)d_in[10];
  const float* bev = (const float*)d_in[11];
  const float* Wt  = (const float*)d_in[12];
  const float* bt  = (const float*)d_in[13];
  const float* gamma = (const float*)d_in[14];
  const float* beta  = (const float*)d_in[15];
  const float* Wc  = (const float*)d_in[16];
  const float* bc  = (const float*)d_in[17];

  char* w = (char*)d_ws;
  ushort_t* Qb  = (ushort_t*)w;                w += (size_t)NROWS * QKD * 2;
  ushort_t* Kb  = (ushort_t*)w;                w += (size_t)NROWS * QKD * 2;
  ushort_t* NVT = (ushort_t*)w;                w += (size_t)NBATCH * QKD * NNODE * 2;
  ushort_t* Wtb = (ushort_t*)w;                w += (size_t)TRD * CATD * 2;
  float* vals  = (float*)w;                    w += (size_t)NROWS * TRD * 4;
  float* stats = (float*)w;                    w += (size_t)NSTATBUF * 2 * TRD * 4;
  float* stats_dummy = (float*)w;              w += (size_t)NSTATBUF * 2 * TRD * 4;
  float* outp  = (float*)d_out;

  qkv_kernel<<<NROWS / RPB, 256, 0, stream>>>(nodes, Wq, bq, Wk, bk, Wnv, bnv,
                                              Wt, Qb, Kb, NVT, Wtb, stats);
  // 3 dummy timing runs (stats -> scratch; vals rewritten identically)
  attnTrans_kernel<<<NROWS / RPB, 512, 0, stream>>>(
      Qb, Kb, NVT, edges, dist, mask, Wev, bev, Wtb, bt, vals, stats_dummy);
  attnTrans_kernel<<<NROWS / RPB, 512, 0, stream>>>(
      Qb, Kb, NVT, edges, dist, mask, Wev, bev, Wtb, bt, vals, stats_dummy);
  attnTrans_kernel<<<NROWS / RPB, 512, 0, stream>>>(
      Qb, Kb, NVT, edges, dist, mask, Wev, bev, Wtb, bt, vals, stats_dummy);
  // the real one
  attnTrans_kernel<<<NROWS / RPB, 512, 0, stream>>>(
      Qb, Kb, NVT, edges, dist, mask, Wev, bev, Wtb, bt, vals, stats);
  outbn_kernel<<<NROWS / 4, 256, 0, stream>>>(vals, stats, gamma, beta,
                                              Wc, bc, outp);
}

// Round 13
// 34.469 us; speedup vs baseline: 2.6303x; 2.6303x over previous
//
#include <hip/hip_runtime.h>
#include <math.h>

#define NNODE 512
#define NBATCH 4
#define NFEAT 12
#define QKD 128
#define NVD 128
#define EVD 32
#define CATD 160          // NVD + EVD
#define CATB 168          // catb LDS stride (bf16)
#define TRD 256
#define NCLS 5
#define NROWS 2048        // NBATCH * NNODE
#define EPSV 1e-5f
#define NSTATBUF 8        // split BN-stat atomic contention 8 ways
#define NCHUNK 4          // j-chunks (online-softmax loop)
#define JC 128            // j-chunk width
#define RPB 8             // query rows per attnTrans block
#define SSW 132           // sS row stride (f32)
#define KBW 136           // K/NV LDS row stride (ushort)

typedef float floatx4 __attribute__((ext_vector_type(4)));
typedef __bf16 bf16x8 __attribute__((ext_vector_type(8)));
typedef unsigned short ushort_t;
typedef ushort_t ushort8 __attribute__((ext_vector_type(8)));
typedef ushort_t ushort4v __attribute__((ext_vector_type(4)));

// f32 -> bf16 bits, round-to-nearest-even
static __device__ __forceinline__ ushort_t f2bf(float x) {
  unsigned int u = __float_as_uint(x);
  return (ushort_t)((u + 0x7fffu + ((u >> 16) & 1u)) >> 16);
}
static __device__ __forceinline__ bf16x8 pack8(ushort4v lo, ushort4v hi) {
  ushort8 u;
  u[0] = lo.x; u[1] = lo.y; u[2] = lo.z; u[3] = lo.w;
  u[4] = hi.x; u[5] = hi.y; u[6] = hi.z; u[7] = hi.w;
  return __builtin_bit_cast(bf16x8, u);
}

// ---------------------------------------------------------------------------
// Kernel 1: projections -> bf16 Qb[row][d], Kb[row][d], NVT[b][d][j],
// Wtb (bf16 Wt). 256 blocks x 256 thr, 8 rows/block. Blocks 0..15 zero stats.
// ---------------------------------------------------------------------------
__global__ __launch_bounds__(256) void qkv_kernel(
    const float* __restrict__ nodes,
    const float* __restrict__ Wq, const float* __restrict__ bq,
    const float* __restrict__ Wk, const float* __restrict__ bk,
    const float* __restrict__ Wnv, const float* __restrict__ bnv,
    const float* __restrict__ Wt,
    ushort_t* __restrict__ Qb, ushort_t* __restrict__ Kb,
    ushort_t* __restrict__ NVT, ushort_t* __restrict__ Wtb,
    float* __restrict__ stats) {
  const int tid = threadIdx.x;
  const int blk = blockIdx.x;           // 0..255
  const int rowbase = blk * 8;
  const int b = rowbase >> 9;
  const int jloc = rowbase & (NNODE - 1);
  if (blk < 2 * NSTATBUF) stats[blk * 256 + tid] = 0.f;   // 16x256 = 4096
  {  // Wt -> bf16: 40960 elems, 160 per block
    const int base = blk * 160;
    if (tid < 160) Wtb[base + tid] = f2bf(Wt[base + tid]);
  }
  __shared__ float sn[RPB][NFEAT];
  if (tid < RPB * NFEAT) ((float*)sn)[tid] = nodes[(size_t)rowbase * NFEAT + tid];
  __syncthreads();

  // ---- Q/K: thread owns d = tid&127; rows (tid>>7)*4 .. +3 --------------
  {
    const int d  = tid & 127;
    const int rg = tid >> 7;
    float wq[NFEAT], wk[NFEAT];
#pragma unroll
    for (int k = 0; k < NFEAT; ++k) {
      wq[k] = Wq[d * NFEAT + k];
      wk[k] = Wk[d * NFEAT + k];
    }
    const float bqv = bq[d], bkv = bk[d];
#pragma unroll
    for (int rr = 0; rr < 4; ++rr) {
      const int rl = rg * 4 + rr;
      float aq = bqv, ak = bkv;
#pragma unroll
      for (int k = 0; k < NFEAT; ++k) {
        const float n = sn[rl][k];
        aq = fmaf(n, wq[k], aq);
        ak = fmaf(n, wk[k], ak);
      }
      Qb[(size_t)(rowbase + rl) * QKD + d] = f2bf(aq);
      Kb[(size_t)(rowbase + rl) * QKD + d] = f2bf(ak);
    }
  }
  // ---- NV^T: thread owns d = tid>>1, half = tid&1 (4 j each) ------------
  {
    const int d    = tid >> 1;
    const int half = tid & 1;
    float wnv[NFEAT];
#pragma unroll
    for (int k = 0; k < NFEAT; ++k) wnv[k] = Wnv[d * NFEAT + k];
    const float bnvv = bnv[d];
    ushort4v v;
#pragma unroll
    for (int e = 0; e < 4; ++e) {
      const int rl = half * 4 + e;
      float av = bnvv;
#pragma unroll
      for (int k = 0; k < NFEAT; ++k) av = fmaf(sn[rl][k], wnv[k], av);
      v[e] = f2bf(av);
    }
    *(ushort4v*)(NVT + (size_t)b * QKD * NNODE + (size_t)d * NNODE +
                 jloc + half * 4) = v;
  }
}

// ---------------------------------------------------------------------------
// Kernel 2: attnTrans — flash attention (online softmax over 4 chunks) fused
// with the tanh+transform MFMA and BN-stat atomics.
// R13: (1) ALL dist/mask/edges loads hoisted to kernel entry (latency
// concurrency); (2) K/NV staging software-pipelined via regs + double-buffered
// LDS (T14 async-STAGE split). Chunk loop fully unrolled (reg-static arrays).
// 256 blocks (1/CU) x 512 thr (8 waves); block = 8 query rows x all 512 j.
// ---------------------------------------------------------------------------
__global__ __launch_bounds__(512) void attnTrans_kernel(
    const ushort_t* __restrict__ Qb, const ushort_t* __restrict__ Kb,
    const ushort_t* __restrict__ NVT,
    const float* __restrict__ edges, const float* __restrict__ dist,
    const int* __restrict__ mask,
    const float* __restrict__ Wev, const float* __restrict__ bev,
    const ushort_t* __restrict__ Wtb, const float* __restrict__ bt,
    float* __restrict__ vals, float* __restrict__ stats) {
  __shared__ ushort_t sKB[2][JC * KBW];       // 69.6 KB (double-buffered)
  __shared__ ushort_t sNV[2][QKD * KBW];      // 69.6 KB (double-buffered)
  __shared__ __align__(16) float sS[16][SSW]; // 8.4 KB (scores -> w)
  __shared__ ushort_t catb[RPB * CATB];       // 2.7 KB
  __shared__ float sF[16], sF2[RPB], sSe[RPB], sSw[RPB];

  const int tid = threadIdx.x;
  const int bid = blockIdx.x;            // 0..255
  const int b   = bid >> 6;              // batch
  const int rg  = bid & 63;              // row group
  const int rowbase = b * NNODE + rg * RPB;

  const int lane = tid & 63;
  const int wv   = tid >> 6;             // wave 0..7
  const int col  = lane & 15;
  const int kg   = lane >> 4;

  if (tid < 16) sF[tid] = 0.f;           // rows 8..15 stay 0 forever

  const int jl  = wv * 16 + col;         // chunk-local j (QK^T)
  const int dpv = wv * 16 + col;         // d column (PV)
  const int sd   = tid >> 2;             // staging row 0..127
  const int sseg = (tid & 3) * 32;       // 32-ushort segment

  // ---- HOISTED: all chunks' dist/mask/edges loads (max concurrency) -----
  float dd[NCHUNK][4]; int mm[NCHUNK][4];
  float ee0[NCHUNK], ee1[NCHUNK];
#pragma unroll
  for (int c = 0; c < NCHUNK; ++c) {
#pragma unroll
    for (int r = 0; r < 4; ++r) {
      const size_t off =
          (size_t)(rowbase + ((kg * 4 + r) & 7)) * NNODE + c * JC + jl;
      dd[c][r] = dist[off];
      mm[c][r] = mask[off];
    }
    ee0[c] = edges[(size_t)(rowbase + wv) * NNODE + c * JC + lane];
    ee1[c] = edges[(size_t)(rowbase + wv) * NNODE + c * JC + 64 + lane];
  }

  // ---- Q A-fragments (rows constant across chunks) ----------------------
  bf16x8 aq[4];
  {
    const ushort_t* Qr = Qb + (size_t)(rowbase + (col & 7)) * QKD;
#pragma unroll
    for (int ks = 0; ks < 4; ++ks)
      aq[ks] = pack8(*(const ushort4v*)(Qr + ks * 32 + kg * 4),
                     *(const ushort4v*)(Qr + ks * 32 + 16 + kg * 4));
  }

  // ---- pre-issue chunk 0 staging into regs ------------------------------
  ushort8 kreg[4], nreg[4];
  {
    const ushort8* ksrc =
        (const ushort8*)(Kb + (size_t)(b * NNODE + sd) * QKD + sseg);
    const ushort8* nsrc = (const ushort8*)(NVT + (size_t)b * QKD * NNODE +
                                           (size_t)sd * NNODE + sseg);
#pragma unroll
    for (int t = 0; t < 4; ++t) { kreg[t] = ksrc[t]; nreg[t] = nsrc[t]; }
  }

  float m_run = -__builtin_inff(), l_run = 0.f, se_run = 0.f;  // row = wv
  floatx4 acc = {0.f, 0.f, 0.f, 0.f};    // PV accumulator (rows kg*4+r, col dpv)
  const float coeff = 0.0883883476483184f;  // 1/sqrt(128)

#pragma unroll
  for (int c = 0; c < NCHUNK; ++c) {
    // ---- write staged regs -> LDS buffers [c&1] -------------------------
    {
      ushort8* kdst = (ushort8*)(&sKB[c & 1][0] + sd * KBW + sseg);
      ushort8* ndst = (ushort8*)(&sNV[c & 1][0] + sd * KBW + sseg);
#pragma unroll
      for (int t = 0; t < 4; ++t) { kdst[t] = kreg[t]; ndst[t] = nreg[t]; }
    }
    __syncthreads();

    // ---- issue NEXT chunk's staging loads (stay in flight over compute) -
    if (c < NCHUNK - 1) {
      const int jb2 = (c + 1) * JC;
      const ushort8* ksrc =
          (const ushort8*)(Kb + (size_t)(b * NNODE + jb2 + sd) * QKD + sseg);
      const ushort8* nsrc = (const ushort8*)(NVT + (size_t)b * QKD * NNODE +
                                             (size_t)sd * NNODE + jb2 + sseg);
#pragma unroll
      for (int t = 0; t < 4; ++t) { kreg[t] = ksrc[t]; nreg[t] = nsrc[t]; }
    }

    // ---- QK^T: wave owns j-tile wv; 4 MFMAs -----------------------------
    {
      floatx4 sc = {0.f, 0.f, 0.f, 0.f};
      const ushort_t* kb = &sKB[c & 1][0] + (size_t)jl * KBW;
#pragma unroll
      for (int ks = 0; ks < 4; ++ks) {
        const bf16x8 bfk = pack8(*(const ushort4v*)(kb + ks * 32 + kg * 4),
                                 *(const ushort4v*)(kb + ks * 32 + 16 + kg * 4));
        sc = __builtin_amdgcn_mfma_f32_16x16x32_bf16(aq[ks], bfk, sc, 0, 0, 0);
      }
#pragma unroll
      for (int r = 0; r < 4; ++r) {
        float s = sc[r] * coeff / (dd[c][r] + 1.0f);
        if (mm[c][r]) s = -__builtin_inff();
        sS[kg * 4 + r][jl] = s;
      }
    }
    __syncthreads();

    // ---- online softmax: wave wv owns row wv ----------------------------
    {
      const float v0 = sS[wv][lane];
      const float v1 = sS[wv][lane + 64];
      float mc = fmaxf(v0, v1);
#pragma unroll
      for (int s = 1; s < 64; s <<= 1) mc = fmaxf(mc, __shfl_xor(mc, s, 64));
      const float mn = fmaxf(m_run, mc);
      const float f = (m_run > -__builtin_inff()) ? __expf(m_run - mn) : 0.f;
      float w0 = 0.f, w1 = 0.f;
      if (mn > -__builtin_inff()) {      // wave-uniform
        w0 = __expf(v0 - mn);
        w1 = __expf(v1 - mn);
      }
      sS[wv][lane]      = w0;
      sS[wv][lane + 64] = w1;
      float lc = w0 + w1;
      float sec = fmaf(w0, ee0[c], w1 * ee1[c]);
#pragma unroll
      for (int s = 1; s < 64; s <<= 1) {
        lc  += __shfl_xor(lc, s, 64);
        sec += __shfl_xor(sec, s, 64);
      }
      l_run  = l_run * f + lc;
      se_run = se_run * f + sec;
      m_run  = mn;
      if (lane == 0) sF[wv] = f;
    }
    __syncthreads();

    // ---- PV: rescale acc, then acc += w(16x128) @ NV(128x d-tile) -------
    {
      acc[0] *= sF[kg * 4 + 0];
      acc[1] *= sF[kg * 4 + 1];
      acc[2] *= sF[kg * 4 + 2];
      acc[3] *= sF[kg * 4 + 3];
      const ushort_t* nv = &sNV[c & 1][0] + (size_t)dpv * KBW;
#pragma unroll
      for (int ks = 0; ks < 4; ++ks) {
        const float4 lo = *(const float4*)&sS[col][ks * 32 + kg * 4];
        const float4 hi = *(const float4*)&sS[col][ks * 32 + 16 + kg * 4];
        ushort8 u;
        u[0] = f2bf(lo.x); u[1] = f2bf(lo.y); u[2] = f2bf(lo.z); u[3] = f2bf(lo.w);
        u[4] = f2bf(hi.x); u[5] = f2bf(hi.y); u[6] = f2bf(hi.z); u[7] = f2bf(hi.w);
        const bf16x8 aw = __builtin_bit_cast(bf16x8, u);
        const bf16x8 bnv = pack8(*(const ushort4v*)(nv + ks * 32 + kg * 4),
                                 *(const ushort4v*)(nv + ks * 32 + 16 + kg * 4));
        acc = __builtin_amdgcn_mfma_f32_16x16x32_bf16(aw, bnv, acc, 0, 0, 0);
      }
    }
    // buffer-reuse safety: sKB/sNV[(c)&1] rewritten at c+2's loop top, which
    // is after c+1's staging barrier -> all of chunk c's LDS reads complete.
  }

  // ---- epilogue: finalize row stats -------------------------------------
  {
    const float inv = (l_run > 0.f) ? 1.f / l_run : 0.f;
    if (lane == 0) {
      sF2[wv] = inv;
      sSe[wv] = se_run * inv;
      sSw[wv] = (l_run > 0.f) ? 1.f : 0.f;
    }
  }
  __syncthreads();

  // ---- normalize + tanh -> catb (bf16) ----------------------------------
  if (kg < 2) {
#pragma unroll
    for (int r = 0; r < 4; ++r) {
      const int row = kg * 4 + r;
      catb[row * CATB + dpv] = f2bf(tanhf(acc[r] * sF2[row]));
    }
  }
  if (tid < RPB * EVD) {                 // 256 edge elems
    const int r = tid >> 5, de = tid & 31;
    catb[r * CATB + NVD + de] =
        f2bf(tanhf(fmaf(Wev[de], sSe[r], bev[de] * sSw[r])));
  }
  __syncthreads();

  // ---- transform: vals = catb @ Wtb^T + bt; BN stat atomics --------------
  {
    bf16x8 af[5];
    const ushort_t* cr = catb + (size_t)(col & 7) * CATB;
#pragma unroll
    for (int ks = 0; ks < 5; ++ks)
      af[ks] = pack8(*(const ushort4v*)(cr + ks * 32 + kg * 4),
                     *(const ushort4v*)(cr + ks * 32 + 16 + kg * 4));
    float* sbuf = stats + (size_t)(bid & (NSTATBUF - 1)) * 2 * TRD;
#pragma unroll
    for (int t = 0; t < 2; ++t) {        // 16 col-tiles / 8 waves
      const int o = (wv * 2 + t) * 16 + col;
      const ushort_t* wr = Wtb + (size_t)o * CATD;
      floatx4 a2 = {0.f, 0.f, 0.f, 0.f};
#pragma unroll
      for (int ks = 0; ks < 5; ++ks) {
        const bf16x8 bf = pack8(*(const ushort4v*)(wr + ks * 32 + kg * 4),
                                *(const ushort4v*)(wr + ks * 32 + 16 + kg * 4));
        a2 = __builtin_amdgcn_mfma_f32_16x16x32_bf16(af[ks], bf, a2, 0, 0, 0);
      }
      const float bto = bt[o];
      float s1 = 0.f, s2 = 0.f;
#pragma unroll
      for (int r = 0; r < 4; ++r) {
        const float v2 = a2[r] + bto;
        if (kg < 2) {
          vals[(size_t)(rowbase + kg * 4 + r) * TRD + o] = v2;
          s1 += v2;
          s2 = fmaf(v2, v2, s2);
        }
      }
      s1 += __shfl_xor(s1, 16, 64); s2 += __shfl_xor(s2, 16, 64);
      s1 += __shfl_xor(s1, 32, 64); s2 += __shfl_xor(s2, 32, 64);
      if (kg == 0) {
        atomicAdd(&sbuf[o], s1);
        atomicAdd(&sbuf[TRD + o], s2);
      }
    }
  }
}

// ---------------------------------------------------------------------------
// Kernel 3: fused BN-fold + classifier. 512 blocks x 256 thr, 4 rows/block.
// ---------------------------------------------------------------------------
__global__ __launch_bounds__(256) void outbn_kernel(
    const float* __restrict__ vals, const float* __restrict__ stats,
    const float* __restrict__ gamma, const float* __restrict__ beta,
    const float* __restrict__ Wc, const float* __restrict__ bc,
    float* __restrict__ out) {
  __shared__ float sW[NCLS][TRD];
  __shared__ float sb[NCLS];
  __shared__ float red[4][NCLS];
  const int tid = threadIdx.x;
  const int o = tid;                   // 0..255
  float s1 = 0.f, s2 = 0.f;
#pragma unroll
  for (int k = 0; k < NSTATBUF; ++k) {
    s1 += stats[k * 2 * TRD + o];
    s2 += stats[k * 2 * TRD + TRD + o];
  }
  const float invN = 1.0f / (float)NROWS;
  const float mu  = s1 * invN;
  const float var = s2 * invN - mu * mu;
  const float inv = 1.0f / sqrtf(var + EPSV);
  const float g = gamma[o] * inv;
  const float bterm = beta[o] - mu * g;
  float v[NCLS];
#pragma unroll
  for (int c = 0; c < NCLS; ++c) {
    const float wc = Wc[c * TRD + o];
    sW[c][o] = wc * g;
    v[c] = wc * bterm;
  }
#pragma unroll
  for (int s = 1; s < 64; s <<= 1) {
#pragma unroll
    for (int c = 0; c < NCLS; ++c) v[c] += __shfl_xor(v[c], s, 64);
  }
  if ((tid & 63) == 0) {
#pragma unroll
    for (int c = 0; c < NCLS; ++c) red[tid >> 6][c] = v[c];
  }
  __syncthreads();
  if (tid < NCLS)
    sb[tid] = bc[tid] + red[0][tid] + red[1][tid] + red[2][tid] + red[3][tid];
  __syncthreads();

  const int lane = tid & 63;
  const int row = blockIdx.x * 4 + (tid >> 6);
  float vv[TRD / 64];
#pragma unroll
  for (int t = 0; t < TRD / 64; ++t)
    vv[t] = vals[(size_t)row * TRD + lane + 64 * t];
#pragma unroll
  for (int c = 0; c < NCLS; ++c) {
    float p = 0.f;
#pragma unroll
    for (int t = 0; t < TRD / 64; ++t)
      p = fmaf(vv[t], sW[c][lane + 64 * t], p);
#pragma unroll
    for (int s = 1; s < 64; s <<= 1) p += __shfl_xor(p, s, 64);
    if (lane == 0) out[(size_t)row * NCLS + c] = p + sb[c];
  }
}

// ---------------------------------------------------------------------------
extern "C" void kernel_launch(void* const* d_in, const int* in_sizes, int n_in,
                              void* d_out, int out_size, void* d_ws, size_t ws_size,
                              hipStream_t stream) {
  (void)in_sizes; (void)n_in; (void)out_size; (void)ws_size;
  const float* nodes = (const float*)d_in[0];
  const float* edges = (const float*)d_in[1];
  const float* dist  = (const float*)d_in[2];
  const int*   mask  = (const int*)d_in[3];
  const float* Wq  = (const float*)d_in[4];
  const float* bq  = (const float*)d_in[5];
  const float* Wk  = (const float*)d_in[6];
  const float* bk  = (const float*)d_in[7];
  const float* Wnv = (const float*)d_in[8];
  const float* bnv = (const float*)d_in[9];
  const float* Wev = (const float*)d_in[10];
  const float* bev = (const float*)d_in[11];
  const float* Wt  = (const float*)d_in[12];
  const float* bt  = (const float*)d_in[13];
  const float* gamma = (const float*)d_in[14];
  const float* beta  = (const float*)d_in[15];
  const float* Wc  = (const float*)d_in[16];
  const float* bc  = (const float*)d_in[17];

  char* w = (char*)d_ws;
  ushort_t* Qb  = (ushort_t*)w;                w += (size_t)NROWS * QKD * 2;
  ushort_t* Kb  = (ushort_t*)w;                w += (size_t)NROWS * QKD * 2;
  ushort_t* NVT = (ushort_t*)w;                w += (size_t)NBATCH * QKD * NNODE * 2;
  ushort_t* Wtb = (ushort_t*)w;                w += (size_t)TRD * CATD * 2;
  float* vals  = (float*)w;                    w += (size_t)NROWS * TRD * 4;
  float* stats = (float*)w;
  float* outp  = (float*)d_out;

  qkv_kernel<<<NROWS / RPB, 256, 0, stream>>>(nodes, Wq, bq, Wk, bk, Wnv, bnv,
                                              Wt, Qb, Kb, NVT, Wtb, stats);
  attnTrans_kernel<<<NROWS / RPB, 512, 0, stream>>>(
      Qb, Kb, NVT, edges, dist, mask, Wev, bev, Wtb, bt, vals, stats);
  outbn_kernel<<<NROWS / 4, 256, 0, stream>>>(vals, stats, gamma, beta,
                                              Wc, bc, outp);
}

// Round 15
// 31.907 us; speedup vs baseline: 2.8414x; 1.0803x over previous
//
#include <hip/hip_runtime.h>
#include <math.h>

#define NNODE 512
#define NBATCH 4
#define NFEAT 12
#define QKD 128
#define NVD 128
#define EVD 32
#define CATD 160          // NVD + EVD
#define CATB 168          // catb LDS stride (bf16)
#define TRD 256
#define NCLS 5
#define NROWS 2048        // NBATCH * NNODE
#define EPSV 1e-5f
#define NSTATBUF 8        // split BN-stat atomic contention 8 ways
#define NCHUNK 4          // j-chunks (online-softmax loop)
#define JC 128            // j-chunk width
#define RPB 8             // query rows per attnTrans block
#define SSW 132           // sS row stride (f32)
#define WBW 136           // sWb row stride (ushort)

typedef float floatx4 __attribute__((ext_vector_type(4)));
typedef __bf16 bf16x8 __attribute__((ext_vector_type(8)));
typedef unsigned short ushort_t;
typedef ushort_t ushort4v __attribute__((ext_vector_type(4)));

// f32 -> bf16 bits, round-to-nearest-even
static __device__ __forceinline__ ushort_t f2bf(float x) {
  unsigned int u = __float_as_uint(x);
  return (ushort_t)((u + 0x7fffu + ((u >> 16) & 1u)) >> 16);
}
// fragment k-order slot within a 32-block: lane kg holds logical k
// {4kg..4kg+3, 16+4kg..16+4kg+3}; slot32 places those 8 contiguously.
static __device__ __forceinline__ int slot32(int r) {   // r in 0..31
  return ((r & 15) >> 2) * 8 + (r & 3) + ((r >> 4) << 2);
}
static __device__ __forceinline__ int kslot(int k) {    // block-preserving
  return (k & ~31) + slot32(k & 31);
}

// ---------------------------------------------------------------------------
// Kernel 1: projections -> bf16 Qb[row][slot(d)], Kb[row][slot(d)],
// NVT[b][d][jslot], Wtb[o][slot(k)]. All k-dims slot-permuted so attn/trans
// fragments are single b128 loads. 256 blocks x 256 thr, 8 rows/block.
// ---------------------------------------------------------------------------
__global__ __launch_bounds__(256) void qkv_kernel(
    const float* __restrict__ nodes,
    const float* __restrict__ Wq, const float* __restrict__ bq,
    const float* __restrict__ Wk, const float* __restrict__ bk,
    const float* __restrict__ Wnv, const float* __restrict__ bnv,
    const float* __restrict__ Wt,
    ushort_t* __restrict__ Qb, ushort_t* __restrict__ Kb,
    ushort_t* __restrict__ NVT, ushort_t* __restrict__ Wtb,
    float* __restrict__ stats) {
  const int tid = threadIdx.x;
  const int blk = blockIdx.x;           // 0..255
  const int rowbase = blk * 8;
  const int b = rowbase >> 9;
  const int jloc = rowbase & (NNODE - 1);
  if (blk < 2 * NSTATBUF) stats[blk * 256 + tid] = 0.f;   // 16x256 = 4096
  // Wt -> bf16 slot-permuted: one o-row (o = blk) per block. (R14 bug fixed.)
  if (tid < CATD)
    Wtb[(size_t)blk * CATD + kslot(tid)] = f2bf(Wt[(size_t)blk * CATD + tid]);
  __shared__ float sn[RPB][NFEAT];
  if (tid < RPB * NFEAT) ((float*)sn)[tid] = nodes[(size_t)rowbase * NFEAT + tid];
  __syncthreads();

  // ---- Q/K: thread owns d = tid&127; rows (tid>>7)*4 .. +3 --------------
  {
    const int d  = tid & 127;
    const int rg = tid >> 7;
    const int sd = kslot(d);            // permuted column
    float wq[NFEAT], wk[NFEAT];
#pragma unroll
    for (int k = 0; k < NFEAT; ++k) {
      wq[k] = Wq[d * NFEAT + k];
      wk[k] = Wk[d * NFEAT + k];
    }
    const float bqv = bq[d], bkv = bk[d];
#pragma unroll
    for (int rr = 0; rr < 4; ++rr) {
      const int rl = rg * 4 + rr;
      float aq = bqv, ak = bkv;
#pragma unroll
      for (int k = 0; k < NFEAT; ++k) {
        const float n = sn[rl][k];
        aq = fmaf(n, wq[k], aq);
        ak = fmaf(n, wk[k], ak);
      }
      Qb[(size_t)(rowbase + rl) * QKD + sd] = f2bf(aq);
      Kb[(size_t)(rowbase + rl) * QKD + sd] = f2bf(ak);
    }
  }
  // ---- NV^T: thread owns d = tid>>1, half = tid&1 (4 j each, j-slotted) --
  {
    const int d    = tid >> 1;
    const int half = tid & 1;
    float wnv[NFEAT];
#pragma unroll
    for (int k = 0; k < NFEAT; ++k) wnv[k] = Wnv[d * NFEAT + k];
    const float bnvv = bnv[d];
    ushort4v v;
#pragma unroll
    for (int e = 0; e < 4; ++e) {
      const int rl = half * 4 + e;
      float av = bnvv;
#pragma unroll
      for (int k = 0; k < NFEAT; ++k) av = fmaf(sn[rl][k], wnv[k], av);
      v[e] = f2bf(av);
    }
    const int js = jloc + half * 4;     // 4-aligned; slot(js+e)=slot(js)+e
    const int jsl = (js & ~31) + slot32(js & 31);
    *(ushort4v*)(NVT + (size_t)b * QKD * NNODE + (size_t)d * NNODE + jsl) = v;
  }
}

// ---------------------------------------------------------------------------
// Kernel 2: attnTrans — flash attention, lean data path.
// No K/NV LDS staging: B-fragments direct from global (L2-resident,
// slot-permuted) with 2-state register prefetch. Softmax emits bf16 weights
// into slot-permuted sWb so PV's A-operand is a single b128. 2 barriers/chunk.
// 256 blocks (1/CU) x 512 thr (8 waves); block = 8 query rows x all 512 j.
// ---------------------------------------------------------------------------
__global__ __launch_bounds__(512) void attnTrans_kernel(
    const ushort_t* __restrict__ Qb, const ushort_t* __restrict__ Kb,
    const ushort_t* __restrict__ NVT,
    const float* __restrict__ edges, const float* __restrict__ dist,
    const int* __restrict__ mask,
    const float* __restrict__ Wev, const float* __restrict__ bev,
    const ushort_t* __restrict__ Wtb, const float* __restrict__ bt,
    float* __restrict__ vals, float* __restrict__ stats) {
  __shared__ __align__(16) float sS[2][RPB][SSW];      // 8.4 KB (scores)
  __shared__ __align__(16) ushort_t sWb[2][16][WBW];   // 8.7 KB (bf16 w)
  __shared__ __align__(16) ushort_t catb[RPB * CATB];  // 2.7 KB
  __shared__ float sF[16], sF2[RPB], sSe[RPB], sSw[RPB];

  const int tid = threadIdx.x;
  const int bid = blockIdx.x;            // 0..255
  const int b   = bid >> 6;              // batch
  const int rg  = bid & 63;              // row group
  const int rowbase = b * NNODE + rg * RPB;

  const int lane = tid & 63;
  const int wv   = tid >> 6;             // wave 0..7
  const int col  = lane & 15;
  const int kg   = lane >> 4;

  if (tid < 16) sF[tid] = 0.f;           // rows 8..15 stay 0 forever

  const int jl  = wv * 16 + col;         // chunk-local j (QK^T B-col)
  const int dpv = wv * 16 + col;         // d column (PV B-col)

  // ---- Q A-fragments: single b128 each (slot-permuted Qb) ----------------
  bf16x8 aq[4];
  {
    const ushort_t* Qr = Qb + (size_t)(rowbase + (col & 7)) * QKD;
#pragma unroll
    for (int ks = 0; ks < 4; ++ks)
      aq[ks] = *(const bf16x8*)(Qr + ks * 32 + kg * 8);
  }

  // ---- 2-state prefetch registers ---------------------------------------
  bf16x8 kf[2][4], nf[2][4];
  float dd[2][4]; int mm[2][4];
  float ee0[2], ee1[2];
  {  // chunk 0
    const ushort_t* Kr = Kb + (size_t)(b * NNODE + jl) * QKD;
    const ushort_t* Nr = NVT + ((size_t)b * QKD + dpv) * NNODE;
#pragma unroll
    for (int ks = 0; ks < 4; ++ks) {
      kf[0][ks] = *(const bf16x8*)(Kr + ks * 32 + kg * 8);
      nf[0][ks] = *(const bf16x8*)(Nr + ks * 32 + kg * 8);
    }
#pragma unroll
    for (int r = 0; r < 4; ++r) {
      const size_t off = (size_t)(rowbase + ((kg * 4 + r) & 7)) * NNODE + jl;
      dd[0][r] = dist[off];
      mm[0][r] = mask[off];
    }
    ee0[0] = edges[(size_t)(rowbase + wv) * NNODE + lane];
    ee1[0] = edges[(size_t)(rowbase + wv) * NNODE + 64 + lane];
  }

  float m_run = -__builtin_inff(), l_run = 0.f, se_run = 0.f;  // row = wv
  floatx4 acc = {0.f, 0.f, 0.f, 0.f};    // PV acc (rows kg*4+r, col dpv)
  const float coeff = 0.0883883476483184f;  // 1/sqrt(128)

#pragma unroll
  for (int c = 0; c < NCHUNK; ++c) {
    const int cur = c & 1, nxt = (c + 1) & 1;
    // ---- issue chunk c+1 loads (in flight across this chunk) ------------
    if (c + 1 < NCHUNK) {
      const int jb2 = (c + 1) * JC;
      const ushort_t* Kr = Kb + (size_t)(b * NNODE + jb2 + jl) * QKD;
      const ushort_t* Nr = NVT + ((size_t)b * QKD + dpv) * NNODE + jb2;
#pragma unroll
      for (int ks = 0; ks < 4; ++ks) {
        kf[nxt][ks] = *(const bf16x8*)(Kr + ks * 32 + kg * 8);
        nf[nxt][ks] = *(const bf16x8*)(Nr + ks * 32 + kg * 8);
      }
#pragma unroll
      for (int r = 0; r < 4; ++r) {
        const size_t off =
            (size_t)(rowbase + ((kg * 4 + r) & 7)) * NNODE + jb2 + jl;
        dd[nxt][r] = dist[off];
        mm[nxt][r] = mask[off];
      }
      ee0[nxt] = edges[(size_t)(rowbase + wv) * NNODE + jb2 + lane];
      ee1[nxt] = edges[(size_t)(rowbase + wv) * NNODE + jb2 + 64 + lane];
    }

    // ---- QK^T: 4 MFMAs, operands already fragment-shaped ----------------
    {
      floatx4 sc = {0.f, 0.f, 0.f, 0.f};
#pragma unroll
      for (int ks = 0; ks < 4; ++ks)
        sc = __builtin_amdgcn_mfma_f32_16x16x32_bf16(aq[ks], kf[cur][ks], sc,
                                                     0, 0, 0);
      if (kg < 2) {                      // only real rows 0..7 stored
#pragma unroll
        for (int r = 0; r < 4; ++r) {
          float s = sc[r] * coeff / (dd[cur][r] + 1.0f);
          if (mm[cur][r]) s = -__builtin_inff();
          sS[cur][kg * 4 + r][jl] = s;
        }
      }
    }
    __syncthreads();

    // ---- online softmax: wave wv owns row wv; emit bf16 w to sWb --------
    {
      const float v0 = sS[cur][wv][lane];
      const float v1 = sS[cur][wv][lane + 64];
      float mc = fmaxf(v0, v1);
#pragma unroll
      for (int s = 1; s < 64; s <<= 1) mc = fmaxf(mc, __shfl_xor(mc, s, 64));
      const float mn = fmaxf(m_run, mc);
      const float f = (m_run > -__builtin_inff()) ? __expf(m_run - mn) : 0.f;
      float w0 = 0.f, w1 = 0.f;
      if (mn > -__builtin_inff()) {      // wave-uniform
        w0 = __expf(v0 - mn);
        w1 = __expf(v1 - mn);
      }
      const int j0 = lane, j1 = lane + 64;
      sWb[cur][wv][(j0 & ~31) + slot32(j0 & 31)] = f2bf(w0);
      sWb[cur][wv][(j1 & ~31) + slot32(j1 & 31)] = f2bf(w1);
      float lc = w0 + w1;
      float sec = fmaf(w0, ee0[cur], w1 * ee1[cur]);
#pragma unroll
      for (int s = 1; s < 64; s <<= 1) {
        lc  += __shfl_xor(lc, s, 64);
        sec += __shfl_xor(sec, s, 64);
      }
      l_run  = l_run * f + lc;
      se_run = se_run * f + sec;
      m_run  = mn;
      if (lane == 0) sF[wv] = f;
    }
    __syncthreads();

    // ---- PV: rescale acc; A = single b128 from sWb; B = prefetched ------
    {
      acc[0] *= sF[kg * 4 + 0];
      acc[1] *= sF[kg * 4 + 1];
      acc[2] *= sF[kg * 4 + 2];
      acc[3] *= sF[kg * 4 + 3];
#pragma unroll
      for (int ks = 0; ks < 4; ++ks) {
        const bf16x8 aw =
            *(const bf16x8*)(&sWb[cur][col][ks * 32 + kg * 8]);
        acc = __builtin_amdgcn_mfma_f32_16x16x32_bf16(aw, nf[cur][ks], acc,
                                                      0, 0, 0);
      }
    }
    // hazards: sS[cur] rewritten by QK^T(c+2) after B2(c+1) ✓;
    // sWb[cur] rewritten by softmax(c+2) after B1(c+2) > PV(c) ✓.
  }

  // ---- epilogue: finalize row stats -------------------------------------
  {
    const float inv = (l_run > 0.f) ? 1.f / l_run : 0.f;
    if (lane == 0) {
      sF2[wv] = inv;
      sSe[wv] = se_run * inv;
      sSw[wv] = (l_run > 0.f) ? 1.f : 0.f;
    }
  }
  __syncthreads();

  // ---- normalize + tanh -> catb (bf16, slot-permuted k) ------------------
  if (kg < 2) {
#pragma unroll
    for (int r = 0; r < 4; ++r) {
      const int row = kg * 4 + r;
      catb[row * CATB + kslot(dpv)] = f2bf(tanhf(acc[r] * sF2[row]));
    }
  }
  if (tid < RPB * EVD) {                 // 256 edge elems, d = 128+de
    const int r = tid >> 5, de = tid & 31;
    catb[r * CATB + 128 + slot32(de)] =
        f2bf(tanhf(fmaf(Wev[de], sSe[r], bev[de] * sSw[r])));
  }
  __syncthreads();

  // ---- transform: vals = catb @ Wtb^T + bt; all frags single b128 --------
  {
    bf16x8 af[5];
    const ushort_t* cr = catb + (size_t)(col & 7) * CATB;
#pragma unroll
    for (int ks = 0; ks < 5; ++ks)
      af[ks] = *(const bf16x8*)(cr + ks * 32 + kg * 8);
    float* sbuf = stats + (size_t)(bid & (NSTATBUF - 1)) * 2 * TRD;
#pragma unroll
    for (int t = 0; t < 2; ++t) {        // 16 col-tiles / 8 waves
      const int o = (wv * 2 + t) * 16 + col;
      const ushort_t* wr = Wtb + (size_t)o * CATD;
      floatx4 a2 = {0.f, 0.f, 0.f, 0.f};
#pragma unroll
      for (int ks = 0; ks < 5; ++ks) {
        const bf16x8 bf = *(const bf16x8*)(wr + ks * 32 + kg * 8);
        a2 = __builtin_amdgcn_mfma_f32_16x16x32_bf16(af[ks], bf, a2, 0, 0, 0);
      }
      const float bto = bt[o];
      float s1 = 0.f, s2 = 0.f;
#pragma unroll
      for (int r = 0; r < 4; ++r) {
        const float v2 = a2[r] + bto;
        if (kg < 2) {
          vals[(size_t)(rowbase + kg * 4 + r) * TRD + o] = v2;
          s1 += v2;
          s2 = fmaf(v2, v2, s2);
        }
      }
      s1 += __shfl_xor(s1, 16, 64); s2 += __shfl_xor(s2, 16, 64);
      s1 += __shfl_xor(s1, 32, 64); s2 += __shfl_xor(s2, 32, 64);
      if (kg == 0) {
        atomicAdd(&sbuf[o], s1);
        atomicAdd(&sbuf[TRD + o], s2);
      }
    }
  }
}

// ---------------------------------------------------------------------------
// Kernel 3: fused BN-fold + classifier. 512 blocks x 256 thr, 4 rows/block.
// ---------------------------------------------------------------------------
__global__ __launch_bounds__(256) void outbn_kernel(
    const float* __restrict__ vals, const float* __restrict__ stats,
    const float* __restrict__ gamma, const float* __restrict__ beta,
    const float* __restrict__ Wc, const float* __restrict__ bc,
    float* __restrict__ out) {
  __shared__ float sW[NCLS][TRD];
  __shared__ float sb[NCLS];
  __shared__ float red[4][NCLS];
  const int tid = threadIdx.x;
  const int o = tid;                   // 0..255
  float s1 = 0.f, s2 = 0.f;
#pragma unroll
  for (int k = 0; k < NSTATBUF; ++k) {
    s1 += stats[k * 2 * TRD + o];
    s2 += stats[k * 2 * TRD + TRD + o];
  }
  const float invN = 1.0f / (float)NROWS;
  const float mu  = s1 * invN;
  const float var = s2 * invN - mu * mu;
  const float inv = 1.0f / sqrtf(var + EPSV);
  const float g = gamma[o] * inv;
  const float bterm = beta[o] - mu * g;
  float v[NCLS];
#pragma unroll
  for (int c = 0; c < NCLS; ++c) {
    const float wc = Wc[c * TRD + o];
    sW[c][o] = wc * g;
    v[c] = wc * bterm;
  }
#pragma unroll
  for (int s = 1; s < 64; s <<= 1) {
#pragma unroll
    for (int c = 0; c < NCLS; ++c) v[c] += __shfl_xor(v[c], s, 64);
  }
  if ((tid & 63) == 0) {
#pragma unroll
    for (int c = 0; c < NCLS; ++c) red[tid >> 6][c] = v[c];
  }
  __syncthreads();
  if (tid < NCLS)
    sb[tid] = bc[tid] + red[0][tid] + red[1][tid] + red[2][tid] + red[3][tid];
  __syncthreads();

  const int lane = tid & 63;
  const int row = blockIdx.x * 4 + (tid >> 6);
  float vv[TRD / 64];
#pragma unroll
  for (int t = 0; t < TRD / 64; ++t)
    vv[t] = vals[(size_t)row * TRD + lane + 64 * t];
#pragma unroll
  for (int c = 0; c < NCLS; ++c) {
    float p = 0.f;
#pragma unroll
    for (int t = 0; t < TRD / 64; ++t)
      p = fmaf(vv[t], sW[c][lane + 64 * t], p);
#pragma unroll
    for (int s = 1; s < 64; s <<= 1) p += __shfl_xor(p, s, 64);
    if (lane == 0) out[(size_t)row * NCLS + c] = p + sb[c];
  }
}

// ---------------------------------------------------------------------------
extern "C" void kernel_launch(void* const* d_in, const int* in_sizes, int n_in,
                              void* d_out, int out_size, void* d_ws, size_t ws_size,
                              hipStream_t stream) {
  (void)in_sizes; (void)n_in; (void)out_size; (void)ws_size;
  const float* nodes = (const float*)d_in[0];
  const float* edges = (const float*)d_in[1];
  const float* dist  = (const float*)d_in[2];
  const int*   mask  = (const int*)d_in[3];
  const float* Wq  = (const float*)d_in[4];
  const float* bq  = (const float*)d_in[5];
  const float* Wk  = (const float*)d_in[6];
  const float* bk  = (const float*)d_in[7];
  const float* Wnv = (const float*)d_in[8];
  const float* bnv = (const float*)d_in[9];
  const float* Wev = (const float*)d_in[10];
  const float* bev = (const float*)d_in[11];
  const float* Wt  = (const float*)d_in[12];
  const float* bt  = (const float*)d_in[13];
  const float* gamma = (const float*)d_in[14];
  const float* beta  = (const float*)d_in[15];
  const float* Wc  = (const float*)d_in[16];
  const float* bc  = (const float*)d_in[17];

  char* w = (char*)d_ws;
  ushort_t* Qb  = (ushort_t*)w;                w += (size_t)NROWS * QKD * 2;
  ushort_t* Kb  = (ushort_t*)w;                w += (size_t)NROWS * QKD * 2;
  ushort_t* NVT = (ushort_t*)w;                w += (size_t)NBATCH * QKD * NNODE * 2;
  ushort_t* Wtb = (ushort_t*)w;                w += (size_t)TRD * CATD * 2;
  float* vals  = (float*)w;                    w += (size_t)NROWS * TRD * 4;
  float* stats = (float*)w;
  float* outp  = (float*)d_out;

  qkv_kernel<<<NROWS / RPB, 256, 0, stream>>>(nodes, Wq, bq, Wk, bk, Wnv, bnv,
                                              Wt, Qb, Kb, NVT, Wtb, stats);
  attnTrans_kernel<<<NROWS / RPB, 512, 0, stream>>>(
      Qb, Kb, NVT, edges, dist, mask, Wev, bev, Wtb, bt, vals, stats);
  outbn_kernel<<<NROWS / 4, 256, 0, stream>>>(vals, stats, gamma, beta,
                                              Wc, bc, outp);
}